// Round 10
// baseline (776.755 us; speedup 1.0000x reference)
//
#include <hip/hip_runtime.h>

typedef __attribute__((ext_vector_type(4))) float f32x4;
typedef __attribute__((ext_vector_type(8))) _Float16 f16x8;

#define NSRC 8192
#define MANC 4096
#define QDIM 4096
#define VDIM 512
#define DM   1024
#define FFD  2048

__device__ __forceinline__ ushort f2h(float f){ _Float16 h=(_Float16)f; return __builtin_bit_cast(ushort,h); }
__device__ __forceinline__ float h2f(ushort u){ _Float16 h=__builtin_bit_cast(_Float16,u); return (float)h; }
__device__ __forceinline__ uint pk2(float a,float b){ return (uint)f2h(a) | ((uint)f2h(b)<<16); }

__device__ __forceinline__ void gload16(const ushort* g, ushort* l){
  __builtin_amdgcn_global_load_lds(
    (const __attribute__((address_space(1))) unsigned int*)g,
    (__attribute__((address_space(3))) unsigned int*)l, 16, 0, 0);
}

// ---------- f32 -> f16 convert (src only) ----------
__global__ __launch_bounds__(256) void k_conv(const float* __restrict__ in, ushort* __restrict__ out, long n){
  long i = ((long)blockIdx.x*256 + threadIdx.x)*8;
  if (i >= n) return;
  float4 a = *(const float4*)(in+i);
  float4 b = *(const float4*)(in+i+4);
  uint4 o; o.x=pk2(a.x,a.y); o.y=pk2(a.z,a.w); o.z=pk2(b.x,b.y); o.w=pk2(b.z,b.w);
  *(uint4*)(out+i) = o;
}

// ---------- merged weight transposes: W[K][N] f32 -> WT[N][K] f16 ----------
__device__ __forceinline__ void tr32(const float* __restrict__ W, ushort* __restrict__ WT,
                                     int K, int N, int bx, int by, int tid){
  __shared__ float tile[32][33];
  int n0 = bx*32, k0 = by*32;
  int tx = tid & 31, ty = tid >> 5;
  #pragma unroll
  for (int i=0;i<4;++i) tile[ty+i*8][tx] = W[(long)(k0+ty+i*8)*N + n0+tx];
  __syncthreads();
  #pragma unroll
  for (int i=0;i<4;++i){ int nn=ty+i*8; WT[(long)(n0+nn)*K + k0+tx] = f2h(tile[tx][nn]); }
}
__global__ __launch_bounds__(256) void k_prep(const float* __restrict__ Wq, const float* __restrict__ Wv,
    const float* __restrict__ W1, const float* __restrict__ W2, const float* __restrict__ Wd,
    ushort* __restrict__ WqT, ushort* __restrict__ WvT, ushort* __restrict__ W1T,
    ushort* __restrict__ W2T, ushort* __restrict__ WdT){
  int b = blockIdx.x, t = threadIdx.x;
  if (b < 4096)                 tr32(Wq, WqT, QDIM, DM,  b % 32,        b / 32,        t);
  else if (b < 4608)            tr32(Wv, WvT, VDIM, DM,  (b-4096)%32,   (b-4096)/32,   t);
  else if (b < 6656)            tr32(W1, W1T, DM,  FFD,  (b-4608)%64,   (b-4608)/64,   t);
  else if (b < 8704)            tr32(W2, W2T, FFD, DM,   (b-6656)%32,   (b-6656)/32,   t);
  else                          tr32(Wd, WdT, DM,  VDIM, (b-8704)%16,   (b-8704)/16,   t);
}

// ============ k_gemmW: 256x256 tile, 8 waves, 128x64 per wave (43.7 FLOP/LDS-byte) ============
// The binding resource at 64x64/wave was the LDS read pipe (FLOP/B=32 < ~40 needed).
// 128x64/wave cuts LDS reads to 24/tile/wave (B-frags reused across mi-halves).
// 512 thr, __launch_bounds__(512,2) -> 256 VGPR/wave (acc[8][4]=128 in unified file).
// LDS 2x64KB double-buffer; stage-all-at-top (8 gload16/thread, >=1 full tile lead);
// 4 MFMA clusters of 16 with setprio; ONE __syncthreads per K-tile.
// EPI: 2 f16 *alpha*extra(f32) | 4 f16 tanh(+bias)
template<int EPI>
__global__ __launch_bounds__(512,2) void k_gemmW(const ushort* __restrict__ A, const ushort* __restrict__ Bt,
    int M, int N, int K, const float* __restrict__ bias, const void* __restrict__ extra,
    float alpha, float* __restrict__ Cf, ushort* __restrict__ Ch, int gxm1, int lg2gx)
{
  extern __shared__ ushort lds[];            // 2 * 32768 shorts = 128KB
  const int tid = threadIdx.x, lane = tid & 63, w = tid >> 6;
  const int wm = (w >> 2) * 128, wn = (w & 3) * 64;
  int id = blockIdx.x;
  int nid = (id & 7) * ((int)gridDim.x >> 3) + (id >> 3);
  const int m0 = (nid >> lg2gx) * 256, n0 = (nid & gxm1) * 256;
  const int lr = lane & 15, kg = lane >> 4;
  f32x4 acc[8][4] = {};
  const int nkt = K >> 6;
  const ushort* Ap = A + (long)m0 * K;
  const ushort* Bp = Bt + (long)n0 * K;
  // staging map: chunk c -> row c>>3, col-chunk (c&7)^(row&7) (XOR swizzle both sides)
  int rj[4], cj[4];
  #pragma unroll
  for (int j = 0; j < 4; ++j){ int c = j*512 + tid; rj[j] = c >> 3; cj[j] = (c & 7) ^ (rj[j] & 7); }
  auto stage = [&](int t, int buf){
    long ko = (long)t * 64;
    ushort* As = lds + buf*32768;
    ushort* Bs = As + 16384;
    #pragma unroll
    for (int j = 0; j < 4; ++j) gload16(Ap + (long)rj[j]*K + ko + cj[j]*8, As + (j*512 + tid)*8);
    #pragma unroll
    for (int j = 0; j < 4; ++j) gload16(Bp + (long)rj[j]*K + ko + cj[j]*8, Bs + (j*512 + tid)*8);
  };
  stage(0, 0);
  __syncthreads();
  int cur = 0;
  for (int t = 0; t < nkt; ++t){
    if (t + 1 < nkt) stage(t + 1, cur ^ 1);   // issued first: full-tile latency lead
    const ushort* Ab = lds + cur*32768;
    const ushort* Bb = Ab + 16384;
    f16x8 af[4], bf[4];
    // ---- cluster 0: mi 0-3, ks0 (reads A-half0 ks0 + B ks0) ----
    #pragma unroll
    for (int mi=0;mi<4;++mi){ int r = wm + mi*16 + lr;      af[mi] = *(const f16x8*)&Ab[r*64 + ((kg ^ (r&7))*8)]; }
    #pragma unroll
    for (int ni=0;ni<4;++ni){ int r = wn + ni*16 + lr;      bf[ni] = *(const f16x8*)&Bb[r*64 + ((kg ^ (r&7))*8)]; }
    __builtin_amdgcn_s_setprio(1);
    #pragma unroll
    for (int mi=0;mi<4;++mi)
      #pragma unroll
      for (int ni=0;ni<4;++ni)
        acc[mi][ni] = __builtin_amdgcn_mfma_f32_16x16x32_f16(af[mi], bf[ni], acc[mi][ni], 0,0,0);
    __builtin_amdgcn_s_setprio(0);
    // ---- cluster 1: mi 4-7, ks0 (reads A-half1 ks0; bf reused) ----
    #pragma unroll
    for (int mi=0;mi<4;++mi){ int r = wm + 64 + mi*16 + lr; af[mi] = *(const f16x8*)&Ab[r*64 + ((kg ^ (r&7))*8)]; }
    __builtin_amdgcn_s_setprio(1);
    #pragma unroll
    for (int mi=0;mi<4;++mi)
      #pragma unroll
      for (int ni=0;ni<4;++ni)
        acc[4+mi][ni] = __builtin_amdgcn_mfma_f32_16x16x32_f16(af[mi], bf[ni], acc[4+mi][ni], 0,0,0);
    __builtin_amdgcn_s_setprio(0);
    // ---- cluster 2: mi 0-3, ks1 ----
    #pragma unroll
    for (int mi=0;mi<4;++mi){ int r = wm + mi*16 + lr;      af[mi] = *(const f16x8*)&Ab[r*64 + (((4+kg) ^ (r&7))*8)]; }
    #pragma unroll
    for (int ni=0;ni<4;++ni){ int r = wn + ni*16 + lr;      bf[ni] = *(const f16x8*)&Bb[r*64 + (((4+kg) ^ (r&7))*8)]; }
    __builtin_amdgcn_s_setprio(1);
    #pragma unroll
    for (int mi=0;mi<4;++mi)
      #pragma unroll
      for (int ni=0;ni<4;++ni)
        acc[mi][ni] = __builtin_amdgcn_mfma_f32_16x16x32_f16(af[mi], bf[ni], acc[mi][ni], 0,0,0);
    __builtin_amdgcn_s_setprio(0);
    // ---- cluster 3: mi 4-7, ks1 (bf reused) ----
    #pragma unroll
    for (int mi=0;mi<4;++mi){ int r = wm + 64 + mi*16 + lr; af[mi] = *(const f16x8*)&Ab[r*64 + (((4+kg) ^ (r&7))*8)]; }
    __builtin_amdgcn_s_setprio(1);
    #pragma unroll
    for (int mi=0;mi<4;++mi)
      #pragma unroll
      for (int ni=0;ni<4;++ni)
        acc[4+mi][ni] = __builtin_amdgcn_mfma_f32_16x16x32_f16(af[mi], bf[ni], acc[4+mi][ni], 0,0,0);
    __builtin_amdgcn_s_setprio(0);
    __syncthreads();                          // drains vm+lgkm: buf^1 staged, buf free
    cur ^= 1;
  }
  // ---- epilogue: per-wave 128x64 via 16x64 LDS slices -> coalesced stores ----
  float* Lw = ((float*)lds) + w*1024;         // 8 waves x 4KB
  #pragma unroll
  for (int mi = 0; mi < 8; ++mi){
    #pragma unroll
    for (int ni = 0; ni < 4; ++ni)
      #pragma unroll
      for (int r = 0; r < 4; ++r)
        Lw[(kg*4+r)*64 + ni*16 + lr] = acc[mi][ni][r];
    __syncthreads();
    #pragma unroll
    for (int tt = 0; tt < 4; ++tt){
      int fi = tt*64 + lane;
      int row16 = fi >> 4, c4 = fi & 15;
      float4 v4 = *(float4*)&Lw[row16*64 + c4*4];
      int row = m0 + wm + mi*16 + row16;
      int col = n0 + wn + c4*4;
      if (EPI==2){
        float4 e4 = *(const float4*)((const float*)extra + (long)row*N + col);
        ushort4 o; o.x=f2h(v4.x*alpha*e4.x); o.y=f2h(v4.y*alpha*e4.y);
        o.z=f2h(v4.z*alpha*e4.z); o.w=f2h(v4.w*alpha*e4.w);
        *(ushort4*)&Ch[(long)row*N + col] = o;
      } else if (EPI==4){
        float4 b4 = *(const float4*)&bias[col];
        ushort4 o; o.x=f2h(tanhf(v4.x+b4.x)); o.y=f2h(tanhf(v4.y+b4.y));
        o.z=f2h(tanhf(v4.z+b4.z)); o.w=f2h(tanhf(v4.w+b4.w));
        *(ushort4*)&Ch[(long)row*N + col] = o;
      }
    }
    __syncthreads();
  }
}

// ============ 16-wave TLP GEMM (round 9): 1024 thr, 256xBN tile, double-buffered ============
template<int EPI, int BIG>
__global__ __launch_bounds__(1024, 4) void k_gemmT(const ushort* __restrict__ A, const ushort* __restrict__ Bt,
    int M, int N, int K, const float* __restrict__ bias, const void* __restrict__ extra,
    float alpha, float* __restrict__ Cf, ushort* __restrict__ Ch, int gxm1, int lg2gx)
{
  extern __shared__ ushort lds[];
  constexpr int BN   = BIG ? 256 : 128;
  constexpr int NI   = BIG ? 4 : 2;
  constexpr int WN   = NI * 16;
  constexpr int BSH  = BIG ? 16384 : 8192;
  constexpr int HALF = 16384 + BSH;
  constexpr int BJ   = BIG ? 2 : 1;
  const int tid = threadIdx.x, lane = tid & 63, w = tid >> 6;
  const int wm = (w >> 2) * 64, wn = (w & 3) * WN;
  int id = blockIdx.x;
  int nid = (id & 7) * ((int)gridDim.x >> 3) + (id >> 3);
  const int m0 = (nid >> lg2gx) * 256, n0 = (nid & gxm1) * BN;
  const int lr = lane & 15, kg = lane >> 4;
  f32x4 acc[4][NI] = {};
  const int nkt = K >> 6;
  const ushort* Ap = A + (long)m0 * K;
  const ushort* Bp = Bt + (long)n0 * K;
  int ra[2], ca[2];
  #pragma unroll
  for (int j = 0; j < 2; ++j){ int c = j*1024 + tid; ra[j] = c >> 3; ca[j] = (c & 7) ^ (ra[j] & 7); }
  auto stage = [&](int t, int buf){
    long ko = (long)t * 64;
    ushort* As = lds + buf*HALF;
    ushort* Bs = As + 16384;
    #pragma unroll
    for (int j = 0; j < 2; ++j)  gload16(Ap + (long)ra[j]*K + ko + ca[j]*8, As + (j*1024 + tid)*8);
    #pragma unroll
    for (int j = 0; j < BJ; ++j) gload16(Bp + (long)ra[j]*K + ko + ca[j]*8, Bs + (j*1024 + tid)*8);
  };
  stage(0, 0);
  __syncthreads();
  int cur = 0;
  for (int t = 0; t < nkt; ++t){
    if (t + 1 < nkt) stage(t + 1, cur ^ 1);
    const ushort* Ab = lds + cur*HALF;
    const ushort* Bb = Ab + 16384;
    f16x8 af[4], bf[NI];
    #pragma unroll
    for (int mi=0;mi<4;++mi){ int r = wm + mi*16 + lr; af[mi] = *(const f16x8*)&Ab[r*64 + ((kg ^ (r&7))*8)]; }
    #pragma unroll
    for (int ni=0;ni<NI;++ni){ int r = wn + ni*16 + lr; bf[ni] = *(const f16x8*)&Bb[r*64 + ((kg ^ (r&7))*8)]; }
    __builtin_amdgcn_s_setprio(1);
    #pragma unroll
    for (int mi=0;mi<4;++mi)
      #pragma unroll
      for (int ni=0;ni<NI;++ni)
        acc[mi][ni] = __builtin_amdgcn_mfma_f32_16x16x32_f16(af[mi], bf[ni], acc[mi][ni], 0,0,0);
    __builtin_amdgcn_s_setprio(0);
    #pragma unroll
    for (int mi=0;mi<4;++mi){ int r = wm + mi*16 + lr; af[mi] = *(const f16x8*)&Ab[r*64 + (((4+kg) ^ (r&7))*8)]; }
    #pragma unroll
    for (int ni=0;ni<NI;++ni){ int r = wn + ni*16 + lr; bf[ni] = *(const f16x8*)&Bb[r*64 + (((4+kg) ^ (r&7))*8)]; }
    __builtin_amdgcn_s_setprio(1);
    #pragma unroll
    for (int mi=0;mi<4;++mi)
      #pragma unroll
      for (int ni=0;ni<NI;++ni)
        acc[mi][ni] = __builtin_amdgcn_mfma_f32_16x16x32_f16(af[mi], bf[ni], acc[mi][ni], 0,0,0);
    __builtin_amdgcn_s_setprio(0);
    __syncthreads();
    cur ^= 1;
  }
  float* Lw = ((float*)lds) + w * 16 * WN;
  #pragma unroll
  for (int mi = 0; mi < 4; ++mi){
    #pragma unroll
    for (int ni = 0; ni < NI; ++ni)
      #pragma unroll
      for (int r = 0; r < 4; ++r)
        Lw[(kg*4+r)*WN + ni*16 + lr] = acc[mi][ni][r];
    __syncthreads();
    #pragma unroll
    for (int tt = 0; tt < WN/16; ++tt){
      int fi = tt*64 + lane;
      int row16 = fi / (WN/4), c4 = fi % (WN/4);
      float4 v4 = *(float4*)&Lw[row16*WN + c4*4];
      int row = m0 + wm + mi*16 + row16;
      int col = n0 + wn + c4*4;
      if (EPI==0){
        float4 b4 = *(const float4*)&bias[col];
        ushort4 o; o.x=f2h(v4.x+b4.x); o.y=f2h(v4.y+b4.y); o.z=f2h(v4.z+b4.z); o.w=f2h(v4.w+b4.w);
        *(ushort4*)&Ch[(long)row*N + col] = o;
      } else if (EPI==3){
        float4 o; o.x=v4.x*alpha; o.y=v4.y*alpha; o.z=v4.z*alpha; o.w=v4.w*alpha;
        *(float4*)&Cf[(long)row*N + col] = o;
      } else if (EPI==5){
        float4 b4 = *(const float4*)&bias[col];
        ushort4 e4 = *(const ushort4*)((const ushort*)extra + (long)row*N + col);
        float4 o; o.x=v4.x+b4.x+h2f(e4.x); o.y=v4.y+b4.y+h2f(e4.y);
        o.z=v4.z+b4.z+h2f(e4.z); o.w=v4.w+b4.w+h2f(e4.w);
        *(float4*)&Cf[(long)row*N + col] = o;
      }
    }
    __syncthreads();
  }
}

// ---------- legacy 128x128 GEMM (for K, V^T, decoder) ----------
// EPI: 0 f16 out +bias | 1 f16 out transposed +bias | 6 f32 out +bias
template<int EPI, bool A32>
__global__ __launch_bounds__(256) void k_gemm(const void* __restrict__ Av, const ushort* __restrict__ Bt,
    int M, int N, int K, const float* __restrict__ bias,
    float alpha, float* __restrict__ Cf, ushort* __restrict__ Ch, int gxm1, int lg2gx)
{
  __shared__ ushort As[128*64];
  __shared__ ushort Bs[128*64];
  const int tid = threadIdx.x, lane = tid & 63, w = tid>>6;
  const int wm = (w>>1)*64, wn = (w&1)*64;
  int id = blockIdx.x;
  int nid = (id & 7)*((int)gridDim.x >> 3) + (id >> 3);
  const int m0 = (nid >> lg2gx)*128, n0 = (nid & gxm1)*128;
  const int lr = lane & 15, kg = lane >> 4;
  f32x4 acc[4][4] = {};
  const int nkt = K >> 6;
  const ushort* Ah = (const ushort*)Av + (A32 ? 0 : (long)m0*K);
  const float*  Af = (const float*)Av  + (A32 ? (long)m0*K : 0);
  const ushort* Bp = Bt + (long)n0*K;
  int rowj[4], colj[4];
  #pragma unroll
  for (int j=0;j<4;++j){
    int c = w*256 + j*64 + lane;
    rowj[j] = c>>3; colj[j] = (c&7) ^ (rowj[j]&7);
  }
  float4 pa[4][2];
  if (A32){
    #pragma unroll
    for (int j=0;j<4;++j){
      const float* s = Af + (long)rowj[j]*K + colj[j]*8;
      pa[j][0] = *(const float4*)s; pa[j][1] = *(const float4*)(s+4);
    }
  }
  for (int kt=0; kt<nkt; ++kt){
    __syncthreads();
    long ko = (long)kt*64;
    if (A32){
      #pragma unroll
      for (int j=0;j<4;++j){
        uint4 o; o.x=pk2(pa[j][0].x,pa[j][0].y); o.y=pk2(pa[j][0].z,pa[j][0].w);
        o.z=pk2(pa[j][1].x,pa[j][1].y); o.w=pk2(pa[j][1].z,pa[j][1].w);
        *(uint4*)&As[(w*256 + j*64 + lane)*8] = o;
      }
    } else {
      #pragma unroll
      for (int j=0;j<4;++j)
        gload16(Ah + (long)rowj[j]*K + ko + colj[j]*8, As + (w*4+j)*512);
    }
    #pragma unroll
    for (int j=0;j<4;++j)
      gload16(Bp + (long)rowj[j]*K + ko + colj[j]*8, Bs + (w*4+j)*512);
    __syncthreads();
    if (A32 && kt+1 < nkt){
      long ko2 = ko + 64;
      #pragma unroll
      for (int j=0;j<4;++j){
        const float* s = Af + (long)rowj[j]*K + ko2 + colj[j]*8;
        pa[j][0] = *(const float4*)s; pa[j][1] = *(const float4*)(s+4);
      }
    }
    #pragma unroll
    for (int ks=0; ks<2; ++ks){
      f16x8 af[4], bfr[4];
      #pragma unroll
      for (int mi=0;mi<4;++mi){
        int r = wm + mi*16 + lr, c = ks*4 + kg;
        af[mi] = *(const f16x8*)&As[r*64 + ((c ^ (r&7))*8)];
      }
      #pragma unroll
      for (int ni=0;ni<4;++ni){
        int r = wn + ni*16 + lr, c = ks*4 + kg;
        bfr[ni] = *(const f16x8*)&Bs[r*64 + ((c ^ (r&7))*8)];
      }
      #pragma unroll
      for (int mi=0;mi<4;++mi)
        #pragma unroll
        for (int ni=0;ni<4;++ni)
          acc[mi][ni] = __builtin_amdgcn_mfma_f32_16x16x32_f16(af[mi], bfr[ni], acc[mi][ni], 0,0,0);
    }
  }
  __syncthreads();
  float* Lw = ((float*)As) + w*1024;
  #pragma unroll
  for (int mi=0;mi<4;++mi){
    #pragma unroll
    for (int ni=0;ni<4;++ni)
      #pragma unroll
      for (int r=0;r<4;++r)
        Lw[(kg*4+r)*64 + ni*16 + lr] = acc[mi][ni][r];
    __syncthreads();
    #pragma unroll
    for (int t=0;t<4;++t){
      int fi = t*64 + lane;
      int row16 = fi >> 4, c4 = fi & 15;
      float4 v4 = *(float4*)&Lw[row16*64 + c4*4];
      int row = m0 + wm + mi*16 + row16;
      int col = n0 + wn + c4*4;
      if (EPI==0){
        float4 b4 = *(const float4*)&bias[col];
        ushort4 o; o.x=f2h(v4.x+b4.x); o.y=f2h(v4.y+b4.y); o.z=f2h(v4.z+b4.z); o.w=f2h(v4.w+b4.w);
        *(ushort4*)&Ch[(long)row*N + col] = o;
      } else if (EPI==1){
        float4 b4 = *(const float4*)&bias[col];
        Ch[(long)(col+0)*M + row] = f2h(v4.x+b4.x);
        Ch[(long)(col+1)*M + row] = f2h(v4.y+b4.y);
        Ch[(long)(col+2)*M + row] = f2h(v4.z+b4.z);
        Ch[(long)(col+3)*M + row] = f2h(v4.w+b4.w);
      } else {
        float4 b4 = *(const float4*)&bias[col];
        float4 o; o.x=v4.x+b4.x; o.y=v4.y+b4.y; o.z=v4.z+b4.z; o.w=v4.w+b4.w;
        *(float4*)&Cf[(long)row*N + col] = o;
      }
    }
    __syncthreads();
  }
}

// ---------- row softmax over 4096 f16 cols, writes prob*512 as f16 ----------
__global__ __launch_bounds__(256) void k_softmax(const ushort* __restrict__ S, ushort* __restrict__ P){
  const long base = (long)blockIdx.x * 4096;
  const int t = threadIdx.x;
  uint u[8];
  *(uint4*)&u[0] = *(const uint4*)(S + base + t*16);
  *(uint4*)&u[4] = *(const uint4*)(S + base + t*16 + 8);
  float v[16];
  #pragma unroll
  for (int i=0;i<8;++i){ v[2*i]=h2f((ushort)(u[i]&0xffff)); v[2*i+1]=h2f((ushort)(u[i]>>16)); }
  float mx = -3.4e38f;
  #pragma unroll
  for (int i=0;i<16;++i) mx = fmaxf(mx, v[i]);
  #pragma unroll
  for (int off=1; off<64; off<<=1) mx = fmaxf(mx, __shfl_xor(mx, off));
  __shared__ float red[8];
  int wv = t>>6;
  if ((t&63)==0) red[wv]=mx;
  __syncthreads();
  mx = fmaxf(fmaxf(red[0],red[1]), fmaxf(red[2],red[3]));
  float e[16]; float sum=0.f;
  #pragma unroll
  for (int i=0;i<16;++i){ e[i]=__expf(v[i]-mx); sum+=e[i]; }
  #pragma unroll
  for (int off=1; off<64; off<<=1) sum += __shfl_xor(sum, off);
  if ((t&63)==0) red[4+wv]=sum;
  __syncthreads();
  sum = red[4]+red[5]+red[6]+red[7];
  float s = 512.f/sum;
  uint o[8];
  #pragma unroll
  for (int i=0;i<8;++i) o[i]=pk2(e[2*i]*s, e[2*i+1]*s);
  *(uint4*)(P + base + t*16)     = *(uint4*)&o[0];
  *(uint4*)(P + base + t*16 + 8) = *(uint4*)&o[4];
}

// ---------- batchnorm: partial sums / finalize / apply ----------
__global__ __launch_bounds__(256) void k_bn_partial(const float* __restrict__ X, float* __restrict__ ps, float* __restrict__ pq, int F, int rowsPer){
  int col = blockIdx.x*256 + threadIdx.x;
  long r0 = (long)blockIdx.y * rowsPer;
  float s=0.f,q=0.f;
  for (int r=0;r<rowsPer;++r){ float x = X[(r0+r)*F + col]; s+=x; q+=x*x; }
  ps[(long)blockIdx.y*F + col]=s; pq[(long)blockIdx.y*F + col]=q;
}
__global__ __launch_bounds__(256) void k_bn_final(const float* __restrict__ ps, const float* __restrict__ pq,
    const float* __restrict__ gamma, const float* __restrict__ beta,
    float* __restrict__ scale, float* __restrict__ shift, int F, float invN, int nch){
  int c = blockIdx.x*256 + threadIdx.x;
  if (c>=F) return;
  float s=0.f,q=0.f;
  for (int i=0;i<nch;++i){ s+=ps[i*F+c]; q+=pq[i*F+c]; }
  float mu = s*invN, var = q*invN - mu*mu;
  float sc = gamma[c]*rsqrtf(var+1e-5f);
  scale[c]=sc; shift[c]=beta[c]-mu*sc;
}
__global__ __launch_bounds__(256) void k_bn_apply(const float* __restrict__ X, const float* __restrict__ scale, const float* __restrict__ shift,
    ushort* __restrict__ Xh, int F, long n){
  long i = ((long)blockIdx.x*256 + threadIdx.x)*4;
  if (i>=n) return;
  int c = (int)(i & (long)(F-1));
  float4 x = *(const float4*)(X+i);
  ushort4 o; o.x=f2h(x.x*scale[c]+shift[c]); o.y=f2h(x.y*scale[c+1]+shift[c+1]);
  o.z=f2h(x.z*scale[c+2]+shift[c+2]); o.w=f2h(x.w*scale[c+3]+shift[c+3]);
  *(ushort4*)(Xh+i)=o;
}
__global__ __launch_bounds__(256) void k_bn_tanh(const float* __restrict__ X, const float* __restrict__ scale, const float* __restrict__ shift,
    float* __restrict__ O, int F, long n){
  long i = ((long)blockIdx.x*256 + threadIdx.x)*4;
  if (i>=n) return;
  int c = (int)(i & (long)(F-1));
  float4 x = *(const float4*)(X+i);
  float4 y; y.x=tanhf(x.x*scale[c]+shift[c]); y.y=tanhf(x.y*scale[c+1]+shift[c+1]);
  y.z=tanhf(x.z*scale[c+2]+shift[c+2]); y.w=tanhf(x.w*scale[c+3]+shift[c+3]);
  *(float4*)(O+i)=y;
}

extern "C" void kernel_launch(void* const* d_in, const int* in_sizes, int n_in,
                              void* d_out, int out_size, void* d_ws, size_t ws_size,
                              hipStream_t stream){
  const float* src = (const float*)d_in[0];
  const float* a1  = (const float*)d_in[1];
  const float* a2  = (const float*)d_in[2];
  const float* lg  = (const float*)d_in[3];
  const float* Wq  = (const float*)d_in[4];
  const float* bq  = (const float*)d_in[5];
  const float* Wv  = (const float*)d_in[6];
  const float* bv  = (const float*)d_in[7];
  const float* W1  = (const float*)d_in[8];
  const float* b1  = (const float*)d_in[9];
  const float* W2  = (const float*)d_in[10];
  const float* b2  = (const float*)d_in[11];
  const float* g1  = (const float*)d_in[12];
  const float* be1 = (const float*)d_in[13];
  const float* g2  = (const float*)d_in[14];
  const float* be2 = (const float*)d_in[15];
  const float* Wd  = (const float*)d_in[16];
  const float* bd  = (const float*)d_in[17];
  const float* gd  = (const float*)d_in[18];
  const float* bed = (const float*)d_in[19];
  char* ws = (char*)d_ws;
  // region R0 (lifetime-aliased): src_h f16 [0,64M) -> scores f16 [0,64M) -> x_att f32 [0,32M)
  ushort* src_h = (ushort*)(ws + 0);
  ushort* scores= (ushort*)(ws + 0);
  float*  x_att = (float*) (ws + 0);
  ushort* xnb   = (ushort*)(ws + 67108864);
  ushort* hbuf  = (ushort*)(ws + 83886080);
  // region R1: prob f16 [128,192M) -> x2 f32 [128,160), x2nb [160,176), y [176,192)
  ushort* prob  = (ushort*)(ws + 134217728);
  float*  x2    = (float*) (ws + 134217728);
  ushort* x2nb  = (ushort*)(ws + 167772160);
  float*  y     = (float*) (ws + 184549376);
  // persistent (>=192MiB)
  ushort* Qh    = (ushort*)(ws + 201326592);
  ushort* Kh    = (ushort*)(ws + 218103808);
  ushort* VTh   = (ushort*)(ws + 226492416);
  ushort* WqT   = (ushort*)(ws + 234881024);
  ushort* WvT   = (ushort*)(ws + 243269632);
  ushort* W1T   = (ushort*)(ws + 244318208);
  ushort* W2T   = (ushort*)(ws + 248512512);
  ushort* WdT   = (ushort*)(ws + 252706816);
  float*  ps    = (float*) (ws + 253755392);
  float*  pq    = (float*) (ws + 253886464);
  float*  sc1   = (float*) (ws + 254017536);
  float*  sh1   = (float*) (ws + 254021632);
  float*  sc2   = (float*) (ws + 254025728);
  float*  sh2   = (float*) (ws + 254029824);
  float*  scd   = (float*) (ws + 254033920);
  float*  shd   = (float*) (ws + 254035968);

  (void)hipFuncSetAttribute((const void*)k_gemmT<0,0>, hipFuncAttributeMaxDynamicSharedMemorySize, 98304);
  (void)hipFuncSetAttribute((const void*)k_gemmT<3,0>, hipFuncAttributeMaxDynamicSharedMemorySize, 98304);
  (void)hipFuncSetAttribute((const void*)k_gemmT<5,0>, hipFuncAttributeMaxDynamicSharedMemorySize, 98304);
  (void)hipFuncSetAttribute((const void*)k_gemmW<2>, hipFuncAttributeMaxDynamicSharedMemorySize, 131072);
  (void)hipFuncSetAttribute((const void*)k_gemmW<4>, hipFuncAttributeMaxDynamicSharedMemorySize, 131072);

  dim3 b256(256), b512(512), b1024(1024);
  k_conv<<<dim3(16384), b256, 0, stream>>>(src, src_h, (long)NSRC*QDIM);
  k_prep<<<dim3(9216), b256, 0, stream>>>(Wq, Wv, W1, W2, Wd, WqT, WvT, W1T, W2T, WdT);
  // Q (SMALL 16-wave), K and V^T (legacy, fused f32 A)
  k_gemmT<0,0><<<dim3(256), b1024, 98304, stream>>>(src_h, WqT, NSRC, DM, QDIM, bq, nullptr, 1.f, nullptr, Qh, 7, 3);
  k_gemm<0,true><<<dim3(256), b256, 0, stream>>>(a1, WqT, MANC, DM, QDIM, bq, 1.f, nullptr, Kh, 7, 3);
  k_gemm<1,true><<<dim3(256), b256, 0, stream>>>(a2, WvT, MANC, DM, VDIM, bv, 1.f, nullptr, VTh, 7, 3);
  // scores(f16) = (Q K^T)/32 * label_graph  [k_gemmW 256x256]
  k_gemmW<2><<<dim3(512), b512, 131072, stream>>>(Qh, Kh, NSRC, MANC, DM, nullptr, lg, 0.03125f, nullptr, scores, 15, 4);
  k_softmax<<<dim3(NSRC), b256, 0, stream>>>(scores, prob);
  k_gemmT<3,0><<<dim3(256), b1024, 98304, stream>>>(prob, VTh, NSRC, DM, MANC, nullptr, nullptr, 1.f/512.f, x_att, nullptr, 7, 3);
  // BN1
  k_bn_partial<<<dim3(DM/256, 32), b256, 0, stream>>>(x_att, ps, pq, DM, NSRC/32);
  k_bn_final<<<dim3(DM/256), b256, 0, stream>>>(ps, pq, g1, be1, sc1, sh1, DM, 1.f/NSRC, 32);
  k_bn_apply<<<dim3(8192), b256, 0, stream>>>(x_att, sc1, sh1, xnb, DM, (long)NSRC*DM);
  // FFN  (FFN1 on k_gemmW 256x256: grid 8x32=256)
  k_gemmW<4><<<dim3(256), b512, 131072, stream>>>(xnb, W1T, NSRC, FFD, DM, b1, nullptr, 1.f, nullptr, hbuf, 7, 3);
  k_gemmT<5,0><<<dim3(256), b1024, 98304, stream>>>(hbuf, W2T, NSRC, DM, FFD, b2, xnb, 1.f, x2, nullptr, 7, 3);
  // BN2
  k_bn_partial<<<dim3(DM/256, 32), b256, 0, stream>>>(x2, ps, pq, DM, NSRC/32);
  k_bn_final<<<dim3(DM/256), b256, 0, stream>>>(ps, pq, g2, be2, sc2, sh2, DM, 1.f/NSRC, 32);
  k_bn_apply<<<dim3(8192), b256, 0, stream>>>(x2, sc2, sh2, x2nb, DM, (long)NSRC*DM);
  // decoder + BN + tanh
  k_gemm<6,false><<<dim3(256), b256, 0, stream>>>(x2nb, WdT, NSRC, VDIM, DM, bd, 1.f, y, nullptr, 3, 2);
  k_bn_partial<<<dim3(VDIM/256, 32), b256, 0, stream>>>(y, ps, pq, VDIM, NSRC/32);
  k_bn_final<<<dim3(2), b256, 0, stream>>>(ps, pq, gd, bed, scd, shd, VDIM, 1.f/NSRC, 32);
  k_bn_tanh<<<dim3(4096), b256, 0, stream>>>(y, scd, shd, (float*)d_out, VDIM, (long)NSRC*VDIM);
}

// Round 11
// 629.198 us; speedup vs baseline: 1.2345x; 1.2345x over previous
//
#include <hip/hip_runtime.h>

typedef __attribute__((ext_vector_type(4))) float f32x4;
typedef __attribute__((ext_vector_type(8))) _Float16 f16x8;

#define NSRC 8192
#define MANC 4096
#define QDIM 4096
#define VDIM 512
#define DM   1024
#define FFD  2048

__device__ __forceinline__ ushort f2h(float f){ _Float16 h=(_Float16)f; return __builtin_bit_cast(ushort,h); }
__device__ __forceinline__ float h2f(ushort u){ _Float16 h=__builtin_bit_cast(_Float16,u); return (float)h; }
__device__ __forceinline__ uint pk2(float a,float b){ return (uint)f2h(a) | ((uint)f2h(b)<<16); }

__device__ __forceinline__ void gload16(const ushort* g, ushort* l){
  __builtin_amdgcn_global_load_lds(
    (const __attribute__((address_space(1))) unsigned int*)g,
    (__attribute__((address_space(3))) unsigned int*)l, 16, 0, 0);
}

// ---------- merged weight transposes + stat-buffer zeroing ----------
__device__ __forceinline__ void tr32(const float* __restrict__ W, ushort* __restrict__ WT,
                                     int K, int N, int bx, int by, int tid){
  __shared__ float tile[32][33];
  int n0 = bx*32, k0 = by*32;
  int tx = tid & 31, ty = tid >> 5;
  #pragma unroll
  for (int i=0;i<4;++i) tile[ty+i*8][tx] = W[(long)(k0+ty+i*8)*N + n0+tx];
  __syncthreads();
  #pragma unroll
  for (int i=0;i<4;++i){ int nn=ty+i*8; WT[(long)(n0+nn)*K + k0+tx] = f2h(tile[tx][nn]); }
}
__global__ __launch_bounds__(256) void k_prep(const float* __restrict__ Wq, const float* __restrict__ Wv,
    const float* __restrict__ W1, const float* __restrict__ W2, const float* __restrict__ Wd,
    ushort* __restrict__ WqT, ushort* __restrict__ WvT, ushort* __restrict__ W1T,
    ushort* __restrict__ W2T, ushort* __restrict__ WdT, float* __restrict__ zbase){
  int b = blockIdx.x, t = threadIdx.x;
  if (b < 4096)                 tr32(Wq, WqT, QDIM, DM,  b % 32,        b / 32,        t);
  else if (b < 4608)            tr32(Wv, WvT, VDIM, DM,  (b-4096)%32,   (b-4096)/32,   t);
  else if (b < 6656)            tr32(W1, W1T, DM,  FFD,  (b-4608)%64,   (b-4608)/64,   t);
  else if (b < 8704)            tr32(W2, W2T, FFD, DM,   (b-6656)%32,   (b-6656)/32,   t);
  else if (b < 9216)            tr32(Wd, WdT, DM,  VDIM, (b-8704)%16,   (b-8704)/16,   t);
  else { for (int i = t; i < 5120; i += 256) zbase[i] = 0.f; }   // ps1,pq1,ps2,pq2,psd,pqd
}

// ============ 16-wave TLP GEMM: 1024 thr, 256xBN tile, double-buffered ============
// __launch_bounds__(1024,4): 1 block/CU -> 128 VGPR cap, no spill (round 9 verified).
// A32: A is f32; reg-load + convert + ds_write (fused conversion; ds_write after MFMA
// so the f32 loads get the whole MFMA phase of latency cover).
// STATS (EPI 3/5): finalize output in acc-space (col fixed per ni), accumulate per-col
// sum/sumsq, shfl-reduce across kg, one atomicAdd per column per block (ps/pq zeroed
// by k_prep). EPI5 adds bias+residual in acc-space.
// EPI: 0 f16+bias | 2 f16 *alpha*extra(f32) | 3 f32 (*alpha, +stats) | 4 f16 tanh(+bias) | 5 f32 (+bias+extra(f16), +stats)
template<int EPI, int BIG, bool A32>
__global__ __launch_bounds__(1024, 4) void k_gemmT(const void* __restrict__ Av, const ushort* __restrict__ Bt,
    int M, int N, int K, const float* __restrict__ bias, const void* __restrict__ extra,
    float alpha, float* __restrict__ Cf, ushort* __restrict__ Ch,
    float* __restrict__ psum, float* __restrict__ pqsum, int gxm1, int lg2gx)
{
  extern __shared__ ushort lds[];
  constexpr int BN   = BIG ? 256 : 128;
  constexpr int NI   = BIG ? 4 : 2;
  constexpr int WN   = NI * 16;
  constexpr int BSH  = BIG ? 16384 : 8192;
  constexpr int HALF = 16384 + BSH;
  constexpr int BJ   = BIG ? 2 : 1;
  const int tid = threadIdx.x, lane = tid & 63, w = tid >> 6;
  const int wm = (w >> 2) * 64, wn = (w & 3) * WN;
  int id = blockIdx.x;
  int nid = (id & 7) * ((int)gridDim.x >> 3) + (id >> 3);
  const int m0 = (nid >> lg2gx) * 256, n0 = (nid & gxm1) * BN;
  const int lr = lane & 15, kg = lane >> 4;
  f32x4 acc[4][NI] = {};
  const int nkt = K >> 6;
  const ushort* Ah = (const ushort*)Av + (A32 ? 0 : (long)m0 * K);
  const float*  Af = (const float*)Av  + (A32 ? (long)m0 * K : 0);
  const ushort* Bp = Bt + (long)n0 * K;
  int ra[2], ca[2];
  #pragma unroll
  for (int j = 0; j < 2; ++j){ int c = j*1024 + tid; ra[j] = c >> 3; ca[j] = (c & 7) ^ (ra[j] & 7); }
  float4 pa[2][2];
  auto loadA32 = [&](int t){
    long ko = (long)t * 64;
    #pragma unroll
    for (int j = 0; j < 2; ++j){
      const float* s = Af + (long)ra[j]*K + ko + ca[j]*8;
      pa[j][0] = *(const float4*)s; pa[j][1] = *(const float4*)(s+4);
    }
  };
  auto writeA32 = [&](int buf){
    ushort* As = lds + buf*HALF;
    #pragma unroll
    for (int j = 0; j < 2; ++j){
      uint4 o; o.x=pk2(pa[j][0].x,pa[j][0].y); o.y=pk2(pa[j][0].z,pa[j][0].w);
      o.z=pk2(pa[j][1].x,pa[j][1].y); o.w=pk2(pa[j][1].z,pa[j][1].w);
      *(uint4*)&As[(j*1024 + tid)*8] = o;
    }
  };
  auto stageA = [&](int t, int buf){
    long ko = (long)t * 64;
    ushort* As = lds + buf*HALF;
    #pragma unroll
    for (int j = 0; j < 2; ++j) gload16(Ah + (long)ra[j]*K + ko + ca[j]*8, As + (j*1024 + tid)*8);
  };
  auto stageB = [&](int t, int buf){
    long ko = (long)t * 64;
    ushort* Bs = lds + buf*HALF + 16384;
    #pragma unroll
    for (int j = 0; j < BJ; ++j) gload16(Bp + (long)ra[j]*K + ko + ca[j]*8, Bs + (j*1024 + tid)*8);
  };
  if (A32){ loadA32(0); writeA32(0); } else stageA(0, 0);
  stageB(0, 0);
  __syncthreads();
  int cur = 0;
  for (int t = 0; t < nkt; ++t){
    const bool st = (t + 1) < nkt;
    if (st){
      if (A32) loadA32(t+1); else stageA(t+1, cur^1);
      stageB(t+1, cur^1);
    }
    const ushort* Ab = lds + cur*HALF;
    const ushort* Bb = Ab + 16384;
    f16x8 af[4], bf[NI];
    #pragma unroll
    for (int mi=0;mi<4;++mi){ int r = wm + mi*16 + lr; af[mi] = *(const f16x8*)&Ab[r*64 + ((kg ^ (r&7))*8)]; }
    #pragma unroll
    for (int ni=0;ni<NI;++ni){ int r = wn + ni*16 + lr; bf[ni] = *(const f16x8*)&Bb[r*64 + ((kg ^ (r&7))*8)]; }
    __builtin_amdgcn_s_setprio(1);
    #pragma unroll
    for (int mi=0;mi<4;++mi)
      #pragma unroll
      for (int ni=0;ni<NI;++ni)
        acc[mi][ni] = __builtin_amdgcn_mfma_f32_16x16x32_f16(af[mi], bf[ni], acc[mi][ni], 0,0,0);
    __builtin_amdgcn_s_setprio(0);
    #pragma unroll
    for (int mi=0;mi<4;++mi){ int r = wm + mi*16 + lr; af[mi] = *(const f16x8*)&Ab[r*64 + (((4+kg) ^ (r&7))*8)]; }
    #pragma unroll
    for (int ni=0;ni<NI;++ni){ int r = wn + ni*16 + lr; bf[ni] = *(const f16x8*)&Bb[r*64 + (((4+kg) ^ (r&7))*8)]; }
    __builtin_amdgcn_s_setprio(1);
    #pragma unroll
    for (int mi=0;mi<4;++mi)
      #pragma unroll
      for (int ni=0;ni<NI;++ni)
        acc[mi][ni] = __builtin_amdgcn_mfma_f32_16x16x32_f16(af[mi], bf[ni], acc[mi][ni], 0,0,0);
    __builtin_amdgcn_s_setprio(0);
    if (A32 && st) writeA32(cur^1);          // f32 loads had the whole MFMA phase to land
    __syncthreads();                          // drains vm+lgkm: buf^1 staged, buf free
    cur ^= 1;
  }
  // ---- stats + acc-space finalize for EPI 3/5 ----
  if (EPI==3 || EPI==5){
    #pragma unroll
    for (int ni=0;ni<NI;++ni){
      int col = n0 + wn + ni*16 + lr;
      float bcol = (EPI==5) ? bias[col] : 0.f;
      float s = 0.f, q = 0.f;
      #pragma unroll
      for (int mi=0;mi<4;++mi){
        #pragma unroll
        for (int r=0;r<4;++r){
          float v = acc[mi][ni][r];
          if (EPI==3) v *= alpha;
          else {
            int row = m0 + wm + mi*16 + kg*4 + r;
            v += bcol + h2f(((const ushort*)extra)[(long)row*N + col]);
          }
          acc[mi][ni][r] = v;
          s += v; q += v*v;
        }
      }
      s += __shfl_xor(s,16); s += __shfl_xor(s,32);
      q += __shfl_xor(q,16); q += __shfl_xor(q,32);
      if (kg==0){ atomicAdd(&psum[col], s); atomicAdd(&pqsum[col], q); }
    }
  }
  // ---- epilogue: per-wave 64xWN transpose via LDS -> coalesced stores ----
  __syncthreads();
  float* Lw = ((float*)lds) + w * 16 * WN;
  #pragma unroll
  for (int mi = 0; mi < 4; ++mi){
    #pragma unroll
    for (int ni = 0; ni < NI; ++ni)
      #pragma unroll
      for (int r = 0; r < 4; ++r)
        Lw[(kg*4+r)*WN + ni*16 + lr] = acc[mi][ni][r];
    __syncthreads();
    #pragma unroll
    for (int tt = 0; tt < WN/16; ++tt){
      int fi = tt*64 + lane;
      int row16 = fi / (WN/4), c4 = fi % (WN/4);
      float4 v4 = *(float4*)&Lw[row16*WN + c4*4];
      int row = m0 + wm + mi*16 + row16;
      int col = n0 + wn + c4*4;
      if (EPI==0){
        float4 b4 = *(const float4*)&bias[col];
        ushort4 o; o.x=f2h(v4.x+b4.x); o.y=f2h(v4.y+b4.y); o.z=f2h(v4.z+b4.z); o.w=f2h(v4.w+b4.w);
        *(ushort4*)&Ch[(long)row*N + col] = o;
      } else if (EPI==2){
        float4 e4 = *(const float4*)((const float*)extra + (long)row*N + col);
        ushort4 o; o.x=f2h(v4.x*alpha*e4.x); o.y=f2h(v4.y*alpha*e4.y);
        o.z=f2h(v4.z*alpha*e4.z); o.w=f2h(v4.w*alpha*e4.w);
        *(ushort4*)&Ch[(long)row*N + col] = o;
      } else if (EPI==3 || EPI==5){
        *(float4*)&Cf[(long)row*N + col] = v4;   // finalized in acc-space
      } else if (EPI==4){
        float4 b4 = *(const float4*)&bias[col];
        ushort4 o; o.x=f2h(tanhf(v4.x+b4.x)); o.y=f2h(tanhf(v4.y+b4.y));
        o.z=f2h(tanhf(v4.z+b4.z)); o.w=f2h(tanhf(v4.w+b4.w));
        *(ushort4*)&Ch[(long)row*N + col] = o;
      }
    }
    __syncthreads();
  }
}

// ---------- legacy 128x128 GEMM (K, V^T, decoder) ----------
// EPI: 0 f16 out +bias | 1 f16 out transposed +bias | 6 f32 out +bias (+stats)
template<int EPI, bool A32>
__global__ __launch_bounds__(256) void k_gemm(const void* __restrict__ Av, const ushort* __restrict__ Bt,
    int M, int N, int K, const float* __restrict__ bias,
    float alpha, float* __restrict__ Cf, ushort* __restrict__ Ch,
    float* __restrict__ psum, float* __restrict__ pqsum, int gxm1, int lg2gx)
{
  __shared__ ushort As[128*64];
  __shared__ ushort Bs[128*64];
  const int tid = threadIdx.x, lane = tid & 63, w = tid>>6;
  const int wm = (w>>1)*64, wn = (w&1)*64;
  int id = blockIdx.x;
  int nid = (id & 7)*((int)gridDim.x >> 3) + (id >> 3);
  const int m0 = (nid >> lg2gx)*128, n0 = (nid & gxm1)*128;
  const int lr = lane & 15, kg = lane >> 4;
  f32x4 acc[4][4] = {};
  const int nkt = K >> 6;
  const ushort* Ah = (const ushort*)Av + (A32 ? 0 : (long)m0*K);
  const float*  Af = (const float*)Av  + (A32 ? (long)m0*K : 0);
  const ushort* Bp = Bt + (long)n0*K;
  int rowj[4], colj[4];
  #pragma unroll
  for (int j=0;j<4;++j){
    int c = w*256 + j*64 + lane;
    rowj[j] = c>>3; colj[j] = (c&7) ^ (rowj[j]&7);
  }
  float4 pa[4][2];
  if (A32){
    #pragma unroll
    for (int j=0;j<4;++j){
      const float* s = Af + (long)rowj[j]*K + colj[j]*8;
      pa[j][0] = *(const float4*)s; pa[j][1] = *(const float4*)(s+4);
    }
  }
  for (int kt=0; kt<nkt; ++kt){
    __syncthreads();
    long ko = (long)kt*64;
    if (A32){
      #pragma unroll
      for (int j=0;j<4;++j){
        uint4 o; o.x=pk2(pa[j][0].x,pa[j][0].y); o.y=pk2(pa[j][0].z,pa[j][0].w);
        o.z=pk2(pa[j][1].x,pa[j][1].y); o.w=pk2(pa[j][1].z,pa[j][1].w);
        *(uint4*)&As[(w*256 + j*64 + lane)*8] = o;
      }
    } else {
      #pragma unroll
      for (int j=0;j<4;++j)
        gload16(Ah + (long)rowj[j]*K + ko + colj[j]*8, As + (w*4+j)*512);
    }
    #pragma unroll
    for (int j=0;j<4;++j)
      gload16(Bp + (long)rowj[j]*K + ko + colj[j]*8, Bs + (w*4+j)*512);
    __syncthreads();
    if (A32 && kt+1 < nkt){
      long ko2 = ko + 64;
      #pragma unroll
      for (int j=0;j<4;++j){
        const float* s = Af + (long)rowj[j]*K + ko2 + colj[j]*8;
        pa[j][0] = *(const float4*)s; pa[j][1] = *(const float4*)(s+4);
      }
    }
    #pragma unroll
    for (int ks=0; ks<2; ++ks){
      f16x8 af[4], bfr[4];
      #pragma unroll
      for (int mi=0;mi<4;++mi){
        int r = wm + mi*16 + lr, c = ks*4 + kg;
        af[mi] = *(const f16x8*)&As[r*64 + ((c ^ (r&7))*8)];
      }
      #pragma unroll
      for (int ni=0;ni<4;++ni){
        int r = wn + ni*16 + lr, c = ks*4 + kg;
        bfr[ni] = *(const f16x8*)&Bs[r*64 + ((c ^ (r&7))*8)];
      }
      #pragma unroll
      for (int mi=0;mi<4;++mi)
        #pragma unroll
        for (int ni=0;ni<4;++ni)
          acc[mi][ni] = __builtin_amdgcn_mfma_f32_16x16x32_f16(af[mi], bfr[ni], acc[mi][ni], 0,0,0);
    }
  }
  if (EPI==6){   // bias + stats in acc-space
    #pragma unroll
    for (int ni=0;ni<4;++ni){
      int col = n0 + wn + ni*16 + lr;
      float bcol = bias[col];
      float s = 0.f, q = 0.f;
      #pragma unroll
      for (int mi=0;mi<4;++mi)
        #pragma unroll
        for (int r=0;r<4;++r){
          float v = acc[mi][ni][r] + bcol;
          acc[mi][ni][r] = v;
          s += v; q += v*v;
        }
      s += __shfl_xor(s,16); s += __shfl_xor(s,32);
      q += __shfl_xor(q,16); q += __shfl_xor(q,32);
      if (kg==0){ atomicAdd(&psum[col], s); atomicAdd(&pqsum[col], q); }
    }
  }
  __syncthreads();
  float* Lw = ((float*)As) + w*1024;
  #pragma unroll
  for (int mi=0;mi<4;++mi){
    #pragma unroll
    for (int ni=0;ni<4;++ni)
      #pragma unroll
      for (int r=0;r<4;++r)
        Lw[(kg*4+r)*64 + ni*16 + lr] = acc[mi][ni][r];
    __syncthreads();
    #pragma unroll
    for (int t=0;t<4;++t){
      int fi = t*64 + lane;
      int row16 = fi >> 4, c4 = fi & 15;
      float4 v4 = *(float4*)&Lw[row16*64 + c4*4];
      int row = m0 + wm + mi*16 + row16;
      int col = n0 + wn + c4*4;
      if (EPI==0){
        float4 b4 = *(const float4*)&bias[col];
        ushort4 o; o.x=f2h(v4.x+b4.x); o.y=f2h(v4.y+b4.y); o.z=f2h(v4.z+b4.z); o.w=f2h(v4.w+b4.w);
        *(ushort4*)&Ch[(long)row*N + col] = o;
      } else if (EPI==1){
        float4 b4 = *(const float4*)&bias[col];
        Ch[(long)(col+0)*M + row] = f2h(v4.x+b4.x);
        Ch[(long)(col+1)*M + row] = f2h(v4.y+b4.y);
        Ch[(long)(col+2)*M + row] = f2h(v4.z+b4.z);
        Ch[(long)(col+3)*M + row] = f2h(v4.w+b4.w);
      } else {
        *(float4*)&Cf[(long)row*N + col] = v4;   // EPI6: bias already applied
      }
    }
    __syncthreads();
  }
}

// ---------- row softmax over 4096 f16 cols, writes prob*512 as f16 ----------
__global__ __launch_bounds__(256) void k_softmax(const ushort* __restrict__ S, ushort* __restrict__ P){
  const long base = (long)blockIdx.x * 4096;
  const int t = threadIdx.x;
  uint u[8];
  *(uint4*)&u[0] = *(const uint4*)(S + base + t*16);
  *(uint4*)&u[4] = *(const uint4*)(S + base + t*16 + 8);
  float v[16];
  #pragma unroll
  for (int i=0;i<8;++i){ v[2*i]=h2f((ushort)(u[i]&0xffff)); v[2*i+1]=h2f((ushort)(u[i]>>16)); }
  float mx = -3.4e38f;
  #pragma unroll
  for (int i=0;i<16;++i) mx = fmaxf(mx, v[i]);
  #pragma unroll
  for (int off=1; off<64; off<<=1) mx = fmaxf(mx, __shfl_xor(mx, off));
  __shared__ float red[8];
  int wv = t>>6;
  if ((t&63)==0) red[wv]=mx;
  __syncthreads();
  mx = fmaxf(fmaxf(red[0],red[1]), fmaxf(red[2],red[3]));
  float e[16]; float sum=0.f;
  #pragma unroll
  for (int i=0;i<16;++i){ e[i]=__expf(v[i]-mx); sum+=e[i]; }
  #pragma unroll
  for (int off=1; off<64; off<<=1) sum += __shfl_xor(sum, off);
  if ((t&63)==0) red[4+wv]=sum;
  __syncthreads();
  sum = red[4]+red[5]+red[6]+red[7];
  float s = 512.f/sum;
  uint o[8];
  #pragma unroll
  for (int i=0;i<8;++i) o[i]=pk2(e[2*i]*s, e[2*i+1]*s);
  *(uint4*)(P + base + t*16)     = *(uint4*)&o[0];
  *(uint4*)(P + base + t*16 + 8) = *(uint4*)&o[4];
}

// ---------- batchnorm: finalize / apply ----------
__global__ __launch_bounds__(256) void k_bn_final(const float* __restrict__ ps, const float* __restrict__ pq,
    const float* __restrict__ gamma, const float* __restrict__ beta,
    float* __restrict__ scale, float* __restrict__ shift, int F, float invN, int nch){
  int c = blockIdx.x*256 + threadIdx.x;
  if (c>=F) return;
  float s=0.f,q=0.f;
  for (int i=0;i<nch;++i){ s+=ps[i*F+c]; q+=pq[i*F+c]; }
  float mu = s*invN, var = q*invN - mu*mu;
  float sc = gamma[c]*rsqrtf(var+1e-5f);
  scale[c]=sc; shift[c]=beta[c]-mu*sc;
}
__global__ __launch_bounds__(256) void k_bn_apply(const float* __restrict__ X, const float* __restrict__ scale, const float* __restrict__ shift,
    ushort* __restrict__ Xh, int F, long n){
  long i = ((long)blockIdx.x*256 + threadIdx.x)*4;
  if (i>=n) return;
  int c = (int)(i & (long)(F-1));
  float4 x = *(const float4*)(X+i);
  ushort4 o; o.x=f2h(x.x*scale[c]+shift[c]); o.y=f2h(x.y*scale[c+1]+shift[c+1]);
  o.z=f2h(x.z*scale[c+2]+shift[c+2]); o.w=f2h(x.w*scale[c+3]+shift[c+3]);
  *(ushort4*)(Xh+i)=o;
}
__global__ __launch_bounds__(256) void k_bn_tanh(const float* __restrict__ X, const float* __restrict__ scale, const float* __restrict__ shift,
    float* __restrict__ O, int F, long n){
  long i = ((long)blockIdx.x*256 + threadIdx.x)*4;
  if (i>=n) return;
  int c = (int)(i & (long)(F-1));
  float4 x = *(const float4*)(X+i);
  float4 y; y.x=tanhf(x.x*scale[c]+shift[c]); y.y=tanhf(x.y*scale[c+1]+shift[c+1]);
  y.z=tanhf(x.z*scale[c+2]+shift[c+2]); y.w=tanhf(x.w*scale[c+3]+shift[c+3]);
  *(float4*)(O+i)=y;
}

extern "C" void kernel_launch(void* const* d_in, const int* in_sizes, int n_in,
                              void* d_out, int out_size, void* d_ws, size_t ws_size,
                              hipStream_t stream){
  const float* src = (const float*)d_in[0];
  const float* a1  = (const float*)d_in[1];
  const float* a2  = (const float*)d_in[2];
  const float* lg  = (const float*)d_in[3];
  const float* Wq  = (const float*)d_in[4];
  const float* bq  = (const float*)d_in[5];
  const float* Wv  = (const float*)d_in[6];
  const float* bv  = (const float*)d_in[7];
  const float* W1  = (const float*)d_in[8];
  const float* b1  = (const float*)d_in[9];
  const float* W2  = (const float*)d_in[10];
  const float* b2  = (const float*)d_in[11];
  const float* g1  = (const float*)d_in[12];
  const float* be1 = (const float*)d_in[13];
  const float* g2  = (const float*)d_in[14];
  const float* be2 = (const float*)d_in[15];
  const float* Wd  = (const float*)d_in[16];
  const float* bd  = (const float*)d_in[17];
  const float* gd  = (const float*)d_in[18];
  const float* bed = (const float*)d_in[19];
  char* ws = (char*)d_ws;
  // region R0: scores f16 [0,64M) -> x_att f32 [0,32M)
  ushort* scores= (ushort*)(ws + 0);
  float*  x_att = (float*) (ws + 0);
  ushort* xnb   = (ushort*)(ws + 67108864);
  ushort* hbuf  = (ushort*)(ws + 83886080);
  // region R1: prob f16 [128,192M) -> x2 f32 [128,160), x2nb [160,176), y [176,192)
  ushort* prob  = (ushort*)(ws + 134217728);
  float*  x2    = (float*) (ws + 134217728);
  ushort* x2nb  = (ushort*)(ws + 167772160);
  float*  y     = (float*) (ws + 184549376);
  // persistent (>=192MiB)
  ushort* Qh    = (ushort*)(ws + 201326592);
  ushort* Kh    = (ushort*)(ws + 218103808);
  ushort* VTh   = (ushort*)(ws + 226492416);
  ushort* WqT   = (ushort*)(ws + 234881024);
  ushort* WvT   = (ushort*)(ws + 243269632);
  ushort* W1T   = (ushort*)(ws + 244318208);
  ushort* W2T   = (ushort*)(ws + 248512512);
  ushort* WdT   = (ushort*)(ws + 252706816);
  float*  sc1   = (float*) (ws + 254017536);
  float*  sh1   = (float*) (ws + 254021632);
  float*  sc2   = (float*) (ws + 254025728);
  float*  sh2   = (float*) (ws + 254029824);
  float*  scd   = (float*) (ws + 254033920);
  float*  shd   = (float*) (ws + 254035968);
  // BN stat buffers (contiguous, zeroed by k_prep): ps1,pq1,ps2,pq2 (1024 each), psd,pqd (512 each)
  float*  ps1   = (float*) (ws + 254038016);
  float*  pq1   = (float*) (ws + 254042112);
  float*  ps2   = (float*) (ws + 254046208);
  float*  pq2   = (float*) (ws + 254050304);
  float*  psd   = (float*) (ws + 254054400);
  float*  pqd   = (float*) (ws + 254056448);

  (void)hipFuncSetAttribute((const void*)k_gemmT<0,0,true>,  hipFuncAttributeMaxDynamicSharedMemorySize, 98304);
  (void)hipFuncSetAttribute((const void*)k_gemmT<2,1,false>, hipFuncAttributeMaxDynamicSharedMemorySize, 131072);
  (void)hipFuncSetAttribute((const void*)k_gemmT<3,0,false>, hipFuncAttributeMaxDynamicSharedMemorySize, 98304);
  (void)hipFuncSetAttribute((const void*)k_gemmT<4,1,false>, hipFuncAttributeMaxDynamicSharedMemorySize, 131072);
  (void)hipFuncSetAttribute((const void*)k_gemmT<5,0,false>, hipFuncAttributeMaxDynamicSharedMemorySize, 98304);

  dim3 b256(256), b1024(1024);
  k_prep<<<dim3(9217), b256, 0, stream>>>(Wq, Wv, W1, W2, Wd, WqT, WvT, W1T, W2T, WdT, ps1);
  // Q (fused f32 conversion), K and V^T (legacy, fused f32 A)
  k_gemmT<0,0,true><<<dim3(256), b1024, 98304, stream>>>(src, WqT, NSRC, DM, QDIM, bq, nullptr, 1.f, nullptr, Qh, nullptr, nullptr, 7, 3);
  k_gemm<0,true><<<dim3(256), b256, 0, stream>>>(a1, WqT, MANC, DM, QDIM, bq, 1.f, nullptr, Kh, nullptr, nullptr, 7, 3);
  k_gemm<1,true><<<dim3(256), b256, 0, stream>>>(a2, WvT, MANC, DM, VDIM, bv, 1.f, nullptr, VTh, nullptr, nullptr, 7, 3);
  // scores(f16) = (Q K^T)/32 * label_graph ; softmax(f16) ; x = prob V (+BN1 stats)
  k_gemmT<2,1,false><<<dim3(512), b1024, 131072, stream>>>(Qh, Kh, NSRC, MANC, DM, nullptr, lg, 0.03125f, nullptr, scores, nullptr, nullptr, 15, 4);
  k_softmax<<<dim3(NSRC), b256, 0, stream>>>(scores, prob);
  k_gemmT<3,0,false><<<dim3(256), b1024, 98304, stream>>>(prob, VTh, NSRC, DM, MANC, nullptr, nullptr, 1.f/512.f, x_att, nullptr, ps1, pq1, 7, 3);
  // BN1
  k_bn_final<<<dim3(DM/256), b256, 0, stream>>>(ps1, pq1, g1, be1, sc1, sh1, DM, 1.f/NSRC, 1);
  k_bn_apply<<<dim3(8192), b256, 0, stream>>>(x_att, sc1, sh1, xnb, DM, (long)NSRC*DM);
  // FFN (FFN2 fuses residual + BN2 stats)
  k_gemmT<4,1,false><<<dim3(256), b1024, 131072, stream>>>(xnb, W1T, NSRC, FFD, DM, b1, nullptr, 1.f, nullptr, hbuf, nullptr, nullptr, 7, 3);
  k_gemmT<5,0,false><<<dim3(256), b1024, 98304, stream>>>(hbuf, W2T, NSRC, DM, FFD, b2, xnb, 1.f, x2, nullptr, ps2, pq2, 7, 3);
  // BN2
  k_bn_final<<<dim3(DM/256), b256, 0, stream>>>(ps2, pq2, g2, be2, sc2, sh2, DM, 1.f/NSRC, 1);
  k_bn_apply<<<dim3(8192), b256, 0, stream>>>(x2, sc2, sh2, x2nb, DM, (long)NSRC*DM);
  // decoder (+BNd stats) + BN + tanh
  k_gemm<6,false><<<dim3(256), b256, 0, stream>>>(x2nb, WdT, NSRC, VDIM, DM, bd, 1.f, y, nullptr, psd, pqd, 3, 2);
  k_bn_final<<<dim3(2), b256, 0, stream>>>(psd, pqd, gd, bed, scd, shd, VDIM, 1.f/NSRC, 1);
  k_bn_tanh<<<dim3(4096), b256, 0, stream>>>(y, scd, shd, (float*)d_out, VDIM, (long)NSRC*VDIM);
}

// Round 12
// 577.029 us; speedup vs baseline: 1.3461x; 1.0904x over previous
//
#include <hip/hip_runtime.h>

typedef __attribute__((ext_vector_type(4))) float f32x4;
typedef __attribute__((ext_vector_type(8))) _Float16 f16x8;

#define NSRC 8192
#define MANC 4096
#define QDIM 4096
#define VDIM 512
#define DM   1024
#define FFD  2048

__device__ __forceinline__ ushort f2h(float f){ _Float16 h=(_Float16)f; return __builtin_bit_cast(ushort,h); }
__device__ __forceinline__ float h2f(ushort u){ _Float16 h=__builtin_bit_cast(_Float16,u); return (float)h; }
__device__ __forceinline__ uint pk2(float a,float b){ return (uint)f2h(a) | ((uint)f2h(b)<<16); }

__device__ __forceinline__ void gload16(const ushort* g, ushort* l){
  __builtin_amdgcn_global_load_lds(
    (const __attribute__((address_space(1))) unsigned int*)g,
    (__attribute__((address_space(3))) unsigned int*)l, 16, 0, 0);
}

// ---------- f32 -> f16 convert (src only) ----------
__global__ __launch_bounds__(256) void k_conv(const float* __restrict__ in, ushort* __restrict__ out, long n){
  long i = ((long)blockIdx.x*256 + threadIdx.x)*8;
  if (i >= n) return;
  float4 a = *(const float4*)(in+i);
  float4 b = *(const float4*)(in+i+4);
  uint4 o; o.x=pk2(a.x,a.y); o.y=pk2(a.z,a.w); o.z=pk2(b.x,b.y); o.w=pk2(b.z,b.w);
  *(uint4*)(out+i) = o;
}

// ---------- merged weight transposes + stat-buffer zeroing ----------
__device__ __forceinline__ void tr32(const float* __restrict__ W, ushort* __restrict__ WT,
                                     int K, int N, int bx, int by, int tid){
  __shared__ float tile[32][33];
  int n0 = bx*32, k0 = by*32;
  int tx = tid & 31, ty = tid >> 5;
  #pragma unroll
  for (int i=0;i<4;++i) tile[ty+i*8][tx] = W[(long)(k0+ty+i*8)*N + n0+tx];
  __syncthreads();
  #pragma unroll
  for (int i=0;i<4;++i){ int nn=ty+i*8; WT[(long)(n0+nn)*K + k0+tx] = f2h(tile[tx][nn]); }
}
__global__ __launch_bounds__(256) void k_prep(const float* __restrict__ Wq, const float* __restrict__ Wv,
    const float* __restrict__ W1, const float* __restrict__ W2, const float* __restrict__ Wd,
    ushort* __restrict__ WqT, ushort* __restrict__ WvT, ushort* __restrict__ W1T,
    ushort* __restrict__ W2T, ushort* __restrict__ WdT, float* __restrict__ zbase){
  int b = blockIdx.x, t = threadIdx.x;
  if (b < 4096)                 tr32(Wq, WqT, QDIM, DM,  b % 32,        b / 32,        t);
  else if (b < 4608)            tr32(Wv, WvT, VDIM, DM,  (b-4096)%32,   (b-4096)/32,   t);
  else if (b < 6656)            tr32(W1, W1T, DM,  FFD,  (b-4608)%64,   (b-4608)/64,   t);
  else if (b < 8704)            tr32(W2, W2T, FFD, DM,   (b-6656)%32,   (b-6656)/32,   t);
  else if (b < 9216)            tr32(Wd, WdT, DM,  VDIM, (b-8704)%16,   (b-8704)/16,   t);
  else { for (int i = t; i < 5120; i += 256) zbase[i] = 0.f; }   // ps1,pq1,ps2,pq2,psd,pqd
}

// ============ 16-wave TLP GEMM: 1024 thr, 256xBN tile, double-buffered ============
// __launch_bounds__(1024,4): 1 block/CU -> 128 VGPR cap, no spill (round 9 verified).
// STATS (EPI 3/5): finalize output in acc-space (col fixed per ni), accumulate per-col
// sum/sumsq, shfl-reduce across kg, one atomicAdd per column per block.
// EPI: 0 f16+bias | 2 f16 *alpha*extra(f32) | 3 f32 (*alpha, +stats) | 4 f16 tanh(+bias) | 5 f32 (+bias+extra(f16), +stats)
template<int EPI, int BIG>
__global__ __launch_bounds__(1024, 4) void k_gemmT(const ushort* __restrict__ A, const ushort* __restrict__ Bt,
    int M, int N, int K, const float* __restrict__ bias, const void* __restrict__ extra,
    float alpha, float* __restrict__ Cf, ushort* __restrict__ Ch,
    float* __restrict__ psum, float* __restrict__ pqsum, int gxm1, int lg2gx)
{
  extern __shared__ ushort lds[];
  constexpr int BN   = BIG ? 256 : 128;
  constexpr int NI   = BIG ? 4 : 2;
  constexpr int WN   = NI * 16;
  constexpr int BSH  = BIG ? 16384 : 8192;
  constexpr int HALF = 16384 + BSH;
  constexpr int BJ   = BIG ? 2 : 1;
  const int tid = threadIdx.x, lane = tid & 63, w = tid >> 6;
  const int wm = (w >> 2) * 64, wn = (w & 3) * WN;
  int id = blockIdx.x;
  int nid = (id & 7) * ((int)gridDim.x >> 3) + (id >> 3);
  const int m0 = (nid >> lg2gx) * 256, n0 = (nid & gxm1) * BN;
  const int lr = lane & 15, kg = lane >> 4;
  f32x4 acc[4][NI] = {};
  const int nkt = K >> 6;
  const ushort* Ap = A + (long)m0 * K;
  const ushort* Bp = Bt + (long)n0 * K;
  int ra[2], ca[2];
  #pragma unroll
  for (int j = 0; j < 2; ++j){ int c = j*1024 + tid; ra[j] = c >> 3; ca[j] = (c & 7) ^ (ra[j] & 7); }
  auto stage = [&](int t, int buf){
    long ko = (long)t * 64;
    ushort* As = lds + buf*HALF;
    ushort* Bs = As + 16384;
    #pragma unroll
    for (int j = 0; j < 2; ++j)  gload16(Ap + (long)ra[j]*K + ko + ca[j]*8, As + (j*1024 + tid)*8);
    #pragma unroll
    for (int j = 0; j < BJ; ++j) gload16(Bp + (long)ra[j]*K + ko + ca[j]*8, Bs + (j*1024 + tid)*8);
  };
  stage(0, 0);
  __syncthreads();
  int cur = 0;
  for (int t = 0; t < nkt; ++t){
    if (t + 1 < nkt) stage(t + 1, cur ^ 1);   // issue first: full-tile latency lead
    const ushort* Ab = lds + cur*HALF;
    const ushort* Bb = Ab + 16384;
    f16x8 af[4], bf[NI];
    #pragma unroll
    for (int mi=0;mi<4;++mi){ int r = wm + mi*16 + lr; af[mi] = *(const f16x8*)&Ab[r*64 + ((kg ^ (r&7))*8)]; }
    #pragma unroll
    for (int ni=0;ni<NI;++ni){ int r = wn + ni*16 + lr; bf[ni] = *(const f16x8*)&Bb[r*64 + ((kg ^ (r&7))*8)]; }
    __builtin_amdgcn_s_setprio(1);
    #pragma unroll
    for (int mi=0;mi<4;++mi)
      #pragma unroll
      for (int ni=0;ni<NI;++ni)
        acc[mi][ni] = __builtin_amdgcn_mfma_f32_16x16x32_f16(af[mi], bf[ni], acc[mi][ni], 0,0,0);
    __builtin_amdgcn_s_setprio(0);
    #pragma unroll
    for (int mi=0;mi<4;++mi){ int r = wm + mi*16 + lr; af[mi] = *(const f16x8*)&Ab[r*64 + (((4+kg) ^ (r&7))*8)]; }
    #pragma unroll
    for (int ni=0;ni<NI;++ni){ int r = wn + ni*16 + lr; bf[ni] = *(const f16x8*)&Bb[r*64 + (((4+kg) ^ (r&7))*8)]; }
    __builtin_amdgcn_s_setprio(1);
    #pragma unroll
    for (int mi=0;mi<4;++mi)
      #pragma unroll
      for (int ni=0;ni<NI;++ni)
        acc[mi][ni] = __builtin_amdgcn_mfma_f32_16x16x32_f16(af[mi], bf[ni], acc[mi][ni], 0,0,0);
    __builtin_amdgcn_s_setprio(0);
    __syncthreads();                          // drains vm+lgkm: buf^1 staged, buf free
    cur ^= 1;
  }
  // ---- stats + acc-space finalize for EPI 3/5 ----
  if (EPI==3 || EPI==5){
    #pragma unroll
    for (int ni=0;ni<NI;++ni){
      int col = n0 + wn + ni*16 + lr;
      float bcol = (EPI==5) ? bias[col] : 0.f;
      float s = 0.f, q = 0.f;
      #pragma unroll
      for (int mi=0;mi<4;++mi){
        #pragma unroll
        for (int r=0;r<4;++r){
          float v = acc[mi][ni][r];
          if (EPI==3) v *= alpha;
          else {
            int row = m0 + wm + mi*16 + kg*4 + r;
            v += bcol + h2f(((const ushort*)extra)[(long)row*N + col]);
          }
          acc[mi][ni][r] = v;
          s += v; q += v*v;
        }
      }
      s += __shfl_xor(s,16); s += __shfl_xor(s,32);
      q += __shfl_xor(q,16); q += __shfl_xor(q,32);
      if (kg==0){ atomicAdd(&psum[col], s); atomicAdd(&pqsum[col], q); }
    }
  }
  // ---- epilogue: per-wave 64xWN transpose via LDS -> coalesced stores ----
  __syncthreads();
  float* Lw = ((float*)lds) + w * 16 * WN;
  #pragma unroll
  for (int mi = 0; mi < 4; ++mi){
    #pragma unroll
    for (int ni = 0; ni < NI; ++ni)
      #pragma unroll
      for (int r = 0; r < 4; ++r)
        Lw[(kg*4+r)*WN + ni*16 + lr] = acc[mi][ni][r];
    __syncthreads();
    #pragma unroll
    for (int tt = 0; tt < WN/16; ++tt){
      int fi = tt*64 + lane;
      int row16 = fi / (WN/4), c4 = fi % (WN/4);
      float4 v4 = *(float4*)&Lw[row16*WN + c4*4];
      int row = m0 + wm + mi*16 + row16;
      int col = n0 + wn + c4*4;
      if (EPI==0){
        float4 b4 = *(const float4*)&bias[col];
        ushort4 o; o.x=f2h(v4.x+b4.x); o.y=f2h(v4.y+b4.y); o.z=f2h(v4.z+b4.z); o.w=f2h(v4.w+b4.w);
        *(ushort4*)&Ch[(long)row*N + col] = o;
      } else if (EPI==2){
        float4 e4 = *(const float4*)((const float*)extra + (long)row*N + col);
        ushort4 o; o.x=f2h(v4.x*alpha*e4.x); o.y=f2h(v4.y*alpha*e4.y);
        o.z=f2h(v4.z*alpha*e4.z); o.w=f2h(v4.w*alpha*e4.w);
        *(ushort4*)&Ch[(long)row*N + col] = o;
      } else if (EPI==3 || EPI==5){
        *(float4*)&Cf[(long)row*N + col] = v4;   // finalized in acc-space
      } else if (EPI==4){
        float4 b4 = *(const float4*)&bias[col];
        ushort4 o; o.x=f2h(tanhf(v4.x+b4.x)); o.y=f2h(tanhf(v4.y+b4.y));
        o.z=f2h(tanhf(v4.z+b4.z)); o.w=f2h(tanhf(v4.w+b4.w));
        *(ushort4*)&Ch[(long)row*N + col] = o;
      }
    }
    __syncthreads();
  }
}

// ---------- legacy 128x128 GEMM (K, V^T, decoder) ----------
// EPI: 0 f16 out +bias | 1 f16 out transposed +bias | 6 f32 out +bias (+stats)
template<int EPI, bool A32>
__global__ __launch_bounds__(256) void k_gemm(const void* __restrict__ Av, const ushort* __restrict__ Bt,
    int M, int N, int K, const float* __restrict__ bias,
    float alpha, float* __restrict__ Cf, ushort* __restrict__ Ch,
    float* __restrict__ psum, float* __restrict__ pqsum, int gxm1, int lg2gx)
{
  __shared__ ushort As[128*64];
  __shared__ ushort Bs[128*64];
  const int tid = threadIdx.x, lane = tid & 63, w = tid>>6;
  const int wm = (w>>1)*64, wn = (w&1)*64;
  int id = blockIdx.x;
  int nid = (id & 7)*((int)gridDim.x >> 3) + (id >> 3);
  const int m0 = (nid >> lg2gx)*128, n0 = (nid & gxm1)*128;
  const int lr = lane & 15, kg = lane >> 4;
  f32x4 acc[4][4] = {};
  const int nkt = K >> 6;
  const ushort* Ah = (const ushort*)Av + (A32 ? 0 : (long)m0*K);
  const float*  Af = (const float*)Av  + (A32 ? (long)m0*K : 0);
  const ushort* Bp = Bt + (long)n0*K;
  int rowj[4], colj[4];
  #pragma unroll
  for (int j=0;j<4;++j){
    int c = w*256 + j*64 + lane;
    rowj[j] = c>>3; colj[j] = (c&7) ^ (rowj[j]&7);
  }
  float4 pa[4][2];
  if (A32){
    #pragma unroll
    for (int j=0;j<4;++j){
      const float* s = Af + (long)rowj[j]*K + colj[j]*8;
      pa[j][0] = *(const float4*)s; pa[j][1] = *(const float4*)(s+4);
    }
  }
  for (int kt=0; kt<nkt; ++kt){
    __syncthreads();
    long ko = (long)kt*64;
    if (A32){
      #pragma unroll
      for (int j=0;j<4;++j){
        uint4 o; o.x=pk2(pa[j][0].x,pa[j][0].y); o.y=pk2(pa[j][0].z,pa[j][0].w);
        o.z=pk2(pa[j][1].x,pa[j][1].y); o.w=pk2(pa[j][1].z,pa[j][1].w);
        *(uint4*)&As[(w*256 + j*64 + lane)*8] = o;
      }
    } else {
      #pragma unroll
      for (int j=0;j<4;++j)
        gload16(Ah + (long)rowj[j]*K + ko + colj[j]*8, As + (w*4+j)*512);
    }
    #pragma unroll
    for (int j=0;j<4;++j)
      gload16(Bp + (long)rowj[j]*K + ko + colj[j]*8, Bs + (w*4+j)*512);
    __syncthreads();
    if (A32 && kt+1 < nkt){
      long ko2 = ko + 64;
      #pragma unroll
      for (int j=0;j<4;++j){
        const float* s = Af + (long)rowj[j]*K + ko2 + colj[j]*8;
        pa[j][0] = *(const float4*)s; pa[j][1] = *(const float4*)(s+4);
      }
    }
    #pragma unroll
    for (int ks=0; ks<2; ++ks){
      f16x8 af[4], bfr[4];
      #pragma unroll
      for (int mi=0;mi<4;++mi){
        int r = wm + mi*16 + lr, c = ks*4 + kg;
        af[mi] = *(const f16x8*)&As[r*64 + ((c ^ (r&7))*8)];
      }
      #pragma unroll
      for (int ni=0;ni<4;++ni){
        int r = wn + ni*16 + lr, c = ks*4 + kg;
        bfr[ni] = *(const f16x8*)&Bs[r*64 + ((c ^ (r&7))*8)];
      }
      #pragma unroll
      for (int mi=0;mi<4;++mi)
        #pragma unroll
        for (int ni=0;ni<4;++ni)
          acc[mi][ni] = __builtin_amdgcn_mfma_f32_16x16x32_f16(af[mi], bfr[ni], acc[mi][ni], 0,0,0);
    }
  }
  if (EPI==6){   // bias + stats in acc-space
    #pragma unroll
    for (int ni=0;ni<4;++ni){
      int col = n0 + wn + ni*16 + lr;
      float bcol = bias[col];
      float s = 0.f, q = 0.f;
      #pragma unroll
      for (int mi=0;mi<4;++mi)
        #pragma unroll
        for (int r=0;r<4;++r){
          float v = acc[mi][ni][r] + bcol;
          acc[mi][ni][r] = v;
          s += v; q += v*v;
        }
      s += __shfl_xor(s,16); s += __shfl_xor(s,32);
      q += __shfl_xor(q,16); q += __shfl_xor(q,32);
      if (kg==0){ atomicAdd(&psum[col], s); atomicAdd(&pqsum[col], q); }
    }
  }
  __syncthreads();
  float* Lw = ((float*)As) + w*1024;
  #pragma unroll
  for (int mi=0;mi<4;++mi){
    #pragma unroll
    for (int ni=0;ni<4;++ni)
      #pragma unroll
      for (int r=0;r<4;++r)
        Lw[(kg*4+r)*64 + ni*16 + lr] = acc[mi][ni][r];
    __syncthreads();
    #pragma unroll
    for (int t=0;t<4;++t){
      int fi = t*64 + lane;
      int row16 = fi >> 4, c4 = fi & 15;
      float4 v4 = *(float4*)&Lw[row16*64 + c4*4];
      int row = m0 + wm + mi*16 + row16;
      int col = n0 + wn + c4*4;
      if (EPI==0){
        float4 b4 = *(const float4*)&bias[col];
        ushort4 o; o.x=f2h(v4.x+b4.x); o.y=f2h(v4.y+b4.y); o.z=f2h(v4.z+b4.z); o.w=f2h(v4.w+b4.w);
        *(ushort4*)&Ch[(long)row*N + col] = o;
      } else if (EPI==1){
        float4 b4 = *(const float4*)&bias[col];
        Ch[(long)(col+0)*M + row] = f2h(v4.x+b4.x);
        Ch[(long)(col+1)*M + row] = f2h(v4.y+b4.y);
        Ch[(long)(col+2)*M + row] = f2h(v4.z+b4.z);
        Ch[(long)(col+3)*M + row] = f2h(v4.w+b4.w);
      } else {
        *(float4*)&Cf[(long)row*N + col] = v4;   // EPI6: bias already applied
      }
    }
    __syncthreads();
  }
}

// ---------- row softmax over 4096 f16 cols, writes prob*512 as f16 ----------
__global__ __launch_bounds__(256) void k_softmax(const ushort* __restrict__ S, ushort* __restrict__ P){
  const long base = (long)blockIdx.x * 4096;
  const int t = threadIdx.x;
  uint u[8];
  *(uint4*)&u[0] = *(const uint4*)(S + base + t*16);
  *(uint4*)&u[4] = *(const uint4*)(S + base + t*16 + 8);
  float v[16];
  #pragma unroll
  for (int i=0;i<8;++i){ v[2*i]=h2f((ushort)(u[i]&0xffff)); v[2*i+1]=h2f((ushort)(u[i]>>16)); }
  float mx = -3.4e38f;
  #pragma unroll
  for (int i=0;i<16;++i) mx = fmaxf(mx, v[i]);
  #pragma unroll
  for (int off=1; off<64; off<<=1) mx = fmaxf(mx, __shfl_xor(mx, off));
  __shared__ float red[8];
  int wv = t>>6;
  if ((t&63)==0) red[wv]=mx;
  __syncthreads();
  mx = fmaxf(fmaxf(red[0],red[1]), fmaxf(red[2],red[3]));
  float e[16]; float sum=0.f;
  #pragma unroll
  for (int i=0;i<16;++i){ e[i]=__expf(v[i]-mx); sum+=e[i]; }
  #pragma unroll
  for (int off=1; off<64; off<<=1) sum += __shfl_xor(sum, off);
  if ((t&63)==0) red[4+wv]=sum;
  __syncthreads();
  sum = red[4]+red[5]+red[6]+red[7];
  float s = 512.f/sum;
  uint o[8];
  #pragma unroll
  for (int i=0;i<8;++i) o[i]=pk2(e[2*i]*s, e[2*i+1]*s);
  *(uint4*)(P + base + t*16)     = *(uint4*)&o[0];
  *(uint4*)(P + base + t*16 + 8) = *(uint4*)&o[4];
}

// ---------- batchnorm: finalize / apply ----------
__global__ __launch_bounds__(256) void k_bn_final(const float* __restrict__ ps, const float* __restrict__ pq,
    const float* __restrict__ gamma, const float* __restrict__ beta,
    float* __restrict__ scale, float* __restrict__ shift, int F, float invN, int nch){
  int c = blockIdx.x*256 + threadIdx.x;
  if (c>=F) return;
  float s=0.f,q=0.f;
  for (int i=0;i<nch;++i){ s+=ps[i*F+c]; q+=pq[i*F+c]; }
  float mu = s*invN, var = q*invN - mu*mu;
  float sc = gamma[c]*rsqrtf(var+1e-5f);
  scale[c]=sc; shift[c]=beta[c]-mu*sc;
}
__global__ __launch_bounds__(256) void k_bn_apply(const float* __restrict__ X, const float* __restrict__ scale, const float* __restrict__ shift,
    ushort* __restrict__ Xh, int F, long n){
  long i = ((long)blockIdx.x*256 + threadIdx.x)*4;
  if (i>=n) return;
  int c = (int)(i & (long)(F-1));
  float4 x = *(const float4*)(X+i);
  ushort4 o; o.x=f2h(x.x*scale[c]+shift[c]); o.y=f2h(x.y*scale[c+1]+shift[c+1]);
  o.z=f2h(x.z*scale[c+2]+shift[c+2]); o.w=f2h(x.w*scale[c+3]+shift[c+3]);
  *(ushort4*)(Xh+i)=o;
}
__global__ __launch_bounds__(256) void k_bn_tanh(const float* __restrict__ X, const float* __restrict__ scale, const float* __restrict__ shift,
    float* __restrict__ O, int F, long n){
  long i = ((long)blockIdx.x*256 + threadIdx.x)*4;
  if (i>=n) return;
  int c = (int)(i & (long)(F-1));
  float4 x = *(const float4*)(X+i);
  float4 y; y.x=tanhf(x.x*scale[c]+shift[c]); y.y=tanhf(x.y*scale[c+1]+shift[c+1]);
  y.z=tanhf(x.z*scale[c+2]+shift[c+2]); y.w=tanhf(x.w*scale[c+3]+shift[c+3]);
  *(float4*)(O+i)=y;
}

extern "C" void kernel_launch(void* const* d_in, const int* in_sizes, int n_in,
                              void* d_out, int out_size, void* d_ws, size_t ws_size,
                              hipStream_t stream){
  const float* src = (const float*)d_in[0];
  const float* a1  = (const float*)d_in[1];
  const float* a2  = (const float*)d_in[2];
  const float* lg  = (const float*)d_in[3];
  const float* Wq  = (const float*)d_in[4];
  const float* bq  = (const float*)d_in[5];
  const float* Wv  = (const float*)d_in[6];
  const float* bv  = (const float*)d_in[7];
  const float* W1  = (const float*)d_in[8];
  const float* b1  = (const float*)d_in[9];
  const float* W2  = (const float*)d_in[10];
  const float* b2  = (const float*)d_in[11];
  const float* g1  = (const float*)d_in[12];
  const float* be1 = (const float*)d_in[13];
  const float* g2  = (const float*)d_in[14];
  const float* be2 = (const float*)d_in[15];
  const float* Wd  = (const float*)d_in[16];
  const float* bd  = (const float*)d_in[17];
  const float* gd  = (const float*)d_in[18];
  const float* bed = (const float*)d_in[19];
  char* ws = (char*)d_ws;
  // region R0: src_h f16 [0,64M) -> scores f16 [0,64M) -> x_att f32 [0,32M)
  ushort* src_h = (ushort*)(ws + 0);
  ushort* scores= (ushort*)(ws + 0);
  float*  x_att = (float*) (ws + 0);
  ushort* xnb   = (ushort*)(ws + 67108864);
  ushort* hbuf  = (ushort*)(ws + 83886080);
  // region R1: prob f16 [128,192M) -> x2 f32 [128,160), x2nb [160,176), y [176,192)
  ushort* prob  = (ushort*)(ws + 134217728);
  float*  x2    = (float*) (ws + 134217728);
  ushort* x2nb  = (ushort*)(ws + 167772160);
  float*  y     = (float*) (ws + 184549376);
  // persistent (>=192MiB)
  ushort* Qh    = (ushort*)(ws + 201326592);
  ushort* Kh    = (ushort*)(ws + 218103808);
  ushort* VTh   = (ushort*)(ws + 226492416);
  ushort* WqT   = (ushort*)(ws + 234881024);
  ushort* WvT   = (ushort*)(ws + 243269632);
  ushort* W1T   = (ushort*)(ws + 244318208);
  ushort* W2T   = (ushort*)(ws + 248512512);
  ushort* WdT   = (ushort*)(ws + 252706816);
  float*  sc1   = (float*) (ws + 254017536);
  float*  sh1   = (float*) (ws + 254021632);
  float*  sc2   = (float*) (ws + 254025728);
  float*  sh2   = (float*) (ws + 254029824);
  float*  scd   = (float*) (ws + 254033920);
  float*  shd   = (float*) (ws + 254035968);
  // BN stat buffers (contiguous, zeroed by k_prep)
  float*  ps1   = (float*) (ws + 254038016);
  float*  pq1   = (float*) (ws + 254042112);
  float*  ps2   = (float*) (ws + 254046208);
  float*  pq2   = (float*) (ws + 254050304);
  float*  psd   = (float*) (ws + 254054400);
  float*  pqd   = (float*) (ws + 254056448);

  (void)hipFuncSetAttribute((const void*)k_gemmT<0,0>, hipFuncAttributeMaxDynamicSharedMemorySize, 98304);
  (void)hipFuncSetAttribute((const void*)k_gemmT<2,1>, hipFuncAttributeMaxDynamicSharedMemorySize, 131072);
  (void)hipFuncSetAttribute((const void*)k_gemmT<3,0>, hipFuncAttributeMaxDynamicSharedMemorySize, 98304);
  (void)hipFuncSetAttribute((const void*)k_gemmT<4,1>, hipFuncAttributeMaxDynamicSharedMemorySize, 131072);
  (void)hipFuncSetAttribute((const void*)k_gemmT<5,0>, hipFuncAttributeMaxDynamicSharedMemorySize, 98304);

  dim3 b256(256), b1024(1024);
  k_conv<<<dim3(16384), b256, 0, stream>>>(src, src_h, (long)NSRC*QDIM);
  k_prep<<<dim3(9217), b256, 0, stream>>>(Wq, Wv, W1, W2, Wd, WqT, WvT, W1T, W2T, WdT, ps1);
  // Q (gload_lds path, round-9 proven), K and V^T (legacy, fused f32 A)
  k_gemmT<0,0><<<dim3(256), b1024, 98304, stream>>>(src_h, WqT, NSRC, DM, QDIM, bq, nullptr, 1.f, nullptr, Qh, nullptr, nullptr, 7, 3);
  k_gemm<0,true><<<dim3(256), b256, 0, stream>>>(a1, WqT, MANC, DM, QDIM, bq, 1.f, nullptr, Kh, nullptr, nullptr, 7, 3);
  k_gemm<1,true><<<dim3(256), b256, 0, stream>>>(a2, WvT, MANC, DM, VDIM, bv, 1.f, nullptr, VTh, nullptr, nullptr, 7, 3);
  // scores(f16) = (Q K^T)/32 * label_graph ; softmax(f16) ; x = prob V (+BN1 stats)
  k_gemmT<2,1><<<dim3(512), b1024, 131072, stream>>>(Qh, Kh, NSRC, MANC, DM, nullptr, lg, 0.03125f, nullptr, scores, nullptr, nullptr, 15, 4);
  k_softmax<<<dim3(NSRC), b256, 0, stream>>>(scores, prob);
  k_gemmT<3,0><<<dim3(256), b1024, 98304, stream>>>(prob, VTh, NSRC, DM, MANC, nullptr, nullptr, 1.f/512.f, x_att, nullptr, ps1, pq1, 7, 3);
  // BN1
  k_bn_final<<<dim3(DM/256), b256, 0, stream>>>(ps1, pq1, g1, be1, sc1, sh1, DM, 1.f/NSRC, 1);
  k_bn_apply<<<dim3(8192), b256, 0, stream>>>(x_att, sc1, sh1, xnb, DM, (long)NSRC*DM);
  // FFN (FFN2 fuses residual + BN2 stats)
  k_gemmT<4,1><<<dim3(256), b1024, 131072, stream>>>(xnb, W1T, NSRC, FFD, DM, b1, nullptr, 1.f, nullptr, hbuf, nullptr, nullptr, 7, 3);
  k_gemmT<5,0><<<dim3(256), b1024, 98304, stream>>>(hbuf, W2T, NSRC, DM, FFD, b2, xnb, 1.f, x2, nullptr, ps2, pq2, 7, 3);
  // BN2
  k_bn_final<<<dim3(DM/256), b256, 0, stream>>>(ps2, pq2, g2, be2, sc2, sh2, DM, 1.f/NSRC, 1);
  k_bn_apply<<<dim3(8192), b256, 0, stream>>>(x2, sc2, sh2, x2nb, DM, (long)NSRC*DM);
  // decoder (+BNd stats) + BN + tanh
  k_gemm<6,false><<<dim3(256), b256, 0, stream>>>(x2nb, WdT, NSRC, VDIM, DM, bd, 1.f, y, nullptr, psd, pqd, 3, 2);
  k_bn_final<<<dim3(2), b256, 0, stream>>>(psd, pqd, gd, bed, scd, shd, VDIM, 1.f/NSRC, 1);
  k_bn_tanh<<<dim3(4096), b256, 0, stream>>>(y, scd, shd, (float*)d_out, VDIM, (long)NSRC*VDIM);
}